// Round 9
// baseline (331.273 us; speedup 1.0000x reference)
//
#include <hip/hip_runtime.h>
#include <hip/hip_fp16.h>
#include <math.h>

#define HW 240
#define PITCH 242           // complex pitch (float4-aligned rows)
#define IMG_PIX (HW*HW)     // 57600
#define NB 15               // 16-wide blocks per image (all passes)
#define TILE_ELEMS (240*16) // elements per blocked chunk
#define CHC 3               // chunks per block, passC  (3840/3 = 1280 blocks)

__device__ __forceinline__ float2 cmul(float2 a, float2 b){
    return make_float2(a.x*b.x - a.y*b.y, a.x*b.y + a.y*b.x);
}
__device__ __forceinline__ float2 cadd(float2 a, float2 b){
    return make_float2(a.x+b.x, a.y+b.y);
}
__device__ __forceinline__ float2 csub(float2 a, float2 b){
    return make_float2(a.x-b.x, a.y-b.y);
}
__device__ __forceinline__ __half2 f2h(float2 a){ return __floats2half2_rn(a.x, a.y); }
__device__ __forceinline__ float2 h2f(__half2 h){ return make_float2(__low2float(h), __high2float(h)); }

// Compiler-only fence: a wave's DS ops execute in issue order on the DS pipe,
// so intra-wave LDS exchanges need no s_barrier (validated R2-R7 on this fft).
__device__ __forceinline__ void wave_fence(){ __builtin_amdgcn_wave_barrier(); }

// Block barrier that drains LDS ONLY (lgkmcnt), leaving global loads in
// flight (vmcnt untouched). Functionally validated R5-R7.
__device__ __forceinline__ void lds_barrier(){
    asm volatile("s_waitcnt lgkmcnt(0)" ::: "memory");
    __builtin_amdgcn_s_barrier();
    asm volatile("" ::: "memory");
}

// ---------- 15-point DFT via Cooley-Tukey 3x5, all-constant twiddles ----------
template<int SIGN>
__device__ __forceinline__ void dft15(const float2* x, float2* X){
    const float S = (float)SIGN;
    const float s3 = 0.8660254037844387f;
    float2 y[5][3];
    #pragma unroll
    for (int n2 = 0; n2 < 5; ++n2){
        float2 a0 = x[n2], a1 = x[5+n2], a2 = x[10+n2];
        float2 t = cadd(a1, a2);
        float2 u = csub(a1, a2);
        float2 m = make_float2(a0.x - 0.5f*t.x, a0.y - 0.5f*t.y);
        float sx = S * s3;
        float2 s = make_float2(-sx*u.y, sx*u.x);
        y[n2][0] = cadd(a0, t);
        y[n2][1] = cadd(m, s);
        y[n2][2] = csub(m, s);
    }
    const float C15[9] = {1.f, 0.9135454576426009f, 0.6691306063588582f, 0.30901699437494745f,
                          -0.10452846326765346f, -0.5f, -0.8090169943749475f,
                          -0.9781476007338057f, -0.9781476007338057f};
    const float S15[9] = {0.f, 0.4067366430758004f, 0.7431448254773942f, 0.9510565162951535f,
                          0.9945218953682733f, 0.8660254037844387f, 0.5877852522924731f,
                          0.20791169081775931f, -0.20791169081775931f};
    #pragma unroll
    for (int n2 = 1; n2 < 5; ++n2){
        #pragma unroll
        for (int k1 = 1; k1 < 3; ++k1){
            const int e = n2*k1;
            y[n2][k1] = cmul(y[n2][k1], make_float2(C15[e], S*S15[e]));
        }
    }
    const float c1 = 0.30901699437494745f, s1 = 0.9510565162951535f;
    const float c2 = -0.8090169943749475f, s2 = 0.5877852522924731f;
    #pragma unroll
    for (int k1 = 0; k1 < 3; ++k1){
        float2 x0 = y[0][k1], x1 = y[1][k1], x2 = y[2][k1], x3 = y[3][k1], x4 = y[4][k1];
        float2 t1 = cadd(x1, x4), t3 = csub(x1, x4);
        float2 t2 = cadd(x2, x3), t4 = csub(x2, x3);
        X[k1] = make_float2(x0.x + t1.x + t2.x, x0.y + t1.y + t2.y);
        float2 u1 = make_float2(x0.x + c1*t1.x + c2*t2.x, x0.y + c1*t1.y + c2*t2.y);
        float2 u2 = make_float2(x0.x + c2*t1.x + c1*t2.x, x0.y + c2*t1.y + c1*t2.y);
        float2 v1 = make_float2(S*(s1*t3.x + s2*t4.x), S*(s1*t3.y + s2*t4.y));
        float2 v2 = make_float2(S*(s2*t3.x - s1*t4.x), S*(s2*t3.y - s1*t4.y));
        X[k1+3]  = make_float2(u1.x - v1.y, u1.y + v1.x);
        X[k1+12] = make_float2(u1.x + v1.y, u1.y - v1.x);
        X[k1+6]  = make_float2(u2.x - v2.y, u2.y + v2.x);
        X[k1+9]  = make_float2(u2.x + v2.y, u2.y - v2.x);
    }
}

// ---------- 16-point DFT via radix-4 x radix-4, all-constant twiddles ----------
template<int SIGN>
__device__ __forceinline__ void dft16(const float2* x, float2* X){
    const float S = (float)SIGN;
    float2 y[4][4];
    #pragma unroll
    for (int n2 = 0; n2 < 4; ++n2){
        float2 a0 = x[n2], a1 = x[4+n2], a2 = x[8+n2], a3 = x[12+n2];
        float2 t0 = cadd(a0,a2), t1 = csub(a0,a2);
        float2 t2 = cadd(a1,a3), t3 = csub(a1,a3);
        float2 it3 = make_float2(-S*t3.y, S*t3.x);
        y[n2][0] = cadd(t0,t2);
        y[n2][2] = csub(t0,t2);
        y[n2][1] = cadd(t1,it3);
        y[n2][3] = csub(t1,it3);
    }
    const float C16[10] = {1.f, 0.9238795325112867f, 0.7071067811865476f, 0.3826834323650898f,
                           0.f, -0.3826834323650898f, -0.7071067811865476f, -0.9238795325112867f,
                           -1.f, -0.9238795325112867f};
    const float S16[10] = {0.f, 0.3826834323650898f, 0.7071067811865476f, 0.9238795325112867f,
                           1.f, 0.9238795325112867f, 0.7071067811865476f, 0.3826834323650898f,
                           0.f, -0.3826834323650898f};
    #pragma unroll
    for (int n2 = 1; n2 < 4; ++n2){
        #pragma unroll
        for (int k1 = 1; k1 < 4; ++k1){
            const int e = n2*k1;
            y[n2][k1] = cmul(y[n2][k1], make_float2(C16[e], S*S16[e]));
        }
    }
    #pragma unroll
    for (int k1 = 0; k1 < 4; ++k1){
        float2 a0 = y[0][k1], a1 = y[1][k1], a2 = y[2][k1], a3 = y[3][k1];
        float2 t0 = cadd(a0,a2), t1 = csub(a0,a2);
        float2 t2 = cadd(a1,a3), t3 = csub(a1,a3);
        float2 it3 = make_float2(-S*t3.y, S*t3.x);
        X[k1]    = cadd(t0,t2);
        X[k1+8]  = csub(t0,t2);
        X[k1+4]  = cadd(t1,it3);
        X[k1+12] = csub(t1,it3);
    }
}

// Cooperative 240-point FFT core. v[a] = x[16a+b] preloaded in registers.
// Leaves results IN REGISTERS: for b<15, XX[m] = X[15m+b]. Row-local (rl)
// LDS exchange only => intra-wave => no block barriers inside.
template<int SIGN>
__device__ __forceinline__ void fft240_core(float2 (*sm)[PITCH], float2* v,
                                            float2* XX, int rl, int b){
    const float TWOPI = 6.28318530717958647692f;
    wave_fence();                    // order vs any prior reads of this row
    float2 Y[15];
    dft15<SIGN>(v, Y);
    float2 step, tw = make_float2(1.0f, 0.0f);
    {
        float ang = (float)SIGN * TWOPI * (float)b * (1.0f/240.0f);
        __sincosf(ang, &step.y, &step.x);
    }
    #pragma unroll
    for (int d = 0; d < 15; ++d){
        sm[rl][b*15 + d] = cmul(Y[d], tw);
        tw = cmul(tw, step);
    }
    wave_fence();
    float2 Z[16];
    if (b < 15){
        #pragma unroll
        for (int bb = 0; bb < 16; ++bb) Z[bb] = sm[rl][bb*15 + b];
    }
    wave_fence();                    // gathers complete before row is reused
    if (b < 15) dft16<SIGN>(Z, XX);
}

// Full FFT: core + scatter so sm[rl][k] = X[k] (passA's Hermitian unpack
// needs cross-lane access to X[240-k]).
template<int SIGN>
__device__ __forceinline__ void fft240(float2 (*sm)[PITCH], float2* v, int rl, int b){
    float2 XX[16];
    fft240_core<SIGN>(sm, v, XX, rl, b);
    if (b < 15){
        #pragma unroll
        for (int m = 0; m < 16; ++m) sm[rl][15*m + b] = XX[m];
    }
    wave_fence();
}

// Intermediate layout L (passB-input-ready), per (img, s, 16-row group A):
//   idx = ((img*15 + s)*15 + A)*256 + c*16 + (h&15),   kw = s*16 + c.
// passB reads v[a] = L[a*256 + rl*16 + b]  -> 256B/wave contiguous, no stage.

// Pass A (REAL-PACKED, 128 threads, one 16-row group per block): 8 packed
// complex FFTs (rows 2r->Re, 2r+1->Im), exact Hermitian unpack to registers,
// LDS transpose to L-tile, fully-coalesced dwordx4 stores.
__global__ __launch_bounds__(128) void passA_rowfft(const float* __restrict__ x,
                                                    __half2* __restrict__ out){
    __shared__ __align__(16) float2 smbuf[8*PITCH];   // 15.1 KB, aliased below
    float2 (*sm)[PITCH] = (float2(*)[PITCH])smbuf;
    __half2* Lh = (__half2*)smbuf;                    // 3840 half2 = 15 KB
    int g = blockIdx.x, img = g / NB, Ag = g % NB, h0 = Ag * 16;
    int tid = threadIdx.x, rl = tid >> 4, b = tid & 15;   // rl in [0,8)
    const float* r0 = x + (size_t)img * IMG_PIX + (size_t)(h0 + 2*rl) * HW;
    float2 v[15];
    #pragma unroll
    for (int a = 0; a < 15; ++a)
        v[a] = make_float2(r0[16*a + b], r0[HW + 16*a + b]);
    fft240<-1>(sm, v, rl, b);               // sm[rl][k] = packed spectrum
    __half2 xa[15], xb[15];
    #pragma unroll
    for (int kb = 0; kb < NB; ++kb){
        int k = kb*16 + b;
        int km = k ? 240 - k : 0;
        float2 P = sm[rl][k], Q = sm[rl][km];   // own row: intra-wave
        xa[kb] = f2h(make_float2(0.5f*(P.x + Q.x), 0.5f*(P.y - Q.y)));  // row h0+2rl
        xb[kb] = f2h(make_float2(0.5f*(P.y + Q.y), 0.5f*(Q.x - P.x)));  // row h0+2rl+1
    }
    lds_barrier();                          // all unpack reads done; alias sm->Lh
    #pragma unroll
    for (int kb = 0; kb < NB; ++kb){        // L-tile: [s=kb][c=b][bb=2rl,2rl+1]
        Lh[kb*256 + b*16 + 2*rl]     = xa[kb];
        Lh[kb*256 + b*16 + 2*rl + 1] = xb[kb];
    }
    lds_barrier();                          // L-tile built
    float4* gout = (float4*)out;
    #pragma unroll
    for (int i = 0; i < 8; ++i){            // 960 float4 units, coalesced
        int u = i*128 + tid;
        if (u < 960){
            int seg = u >> 6, e = u & 63;   // 64 float4 per s-segment
            gout[((size_t)(img*NB + seg)*NB + Ag)*64 + e] = ((float4*)Lh)[u];
        }
    }
}

// Pass B (IN-PLACE, IN-REGISTER COMBINE, ONE BARRIER): direct coalesced
// reg-gather from layout L; forward col FFT (wave-local); DC combine fully in
// registers (thread (rl,b) owns XX[m]=X[kh=15m+b] of col kw0+rl; U read as
// 16B stripes, L2/L3 absorb); wave-local scatter/gather; inverse col FFT;
// single lds_barrier; staged float4 store in [h][c] order for passC.
__global__ __launch_bounds__(256, 4) void passB_col_dc_icol(__half2* __restrict__ io,
                                                            const float* __restrict__ under,
                                                            const float* __restrict__ Am){
    __shared__ __align__(16) float2 sm[16][PITCH];
    int g = blockIdx.x, img = g / NB, s = g % NB, kw0 = s * 16;
    int tid = threadIdx.x, rl = tid >> 4, b = tid & 15;
    __half2* chunk = io + (size_t)(img*NB + s) * TILE_ELEMS;

    float2 v[15];                           // v[a] = element (h=16a+b, kw=kw0+rl)
    #pragma unroll
    for (int a = 0; a < 15; ++a)
        v[a] = h2f(chunk[a*256 + rl*16 + b]);   // 256B/wave contiguous

    float2 XX[16];
    fft240_core<-1>(sm, v, XX, rl, b);      // XX[m] = X[kh=15m+b], col kw0+rl

    const float* y0 = under + (size_t)img * (2*IMG_PIX);
    if (b < 15){
        #pragma unroll
        for (int m = 0; m < 16; ++m){       // in-register DC combine
            size_t p = (size_t)(15*m + b) * HW + kw0 + rl;
            float sc = 1.0f - Am[p];
            XX[m] = make_float2(sc * XX[m].x + y0[p],
                                sc * XX[m].y + y0[IMG_PIX + p]);
        }
        #pragma unroll
        for (int m = 0; m < 16; ++m)        // own-row scatter (wave-local)
            sm[rl][15*m + b] = XX[m];
    }
    wave_fence();
    float2 v2[15];
    #pragma unroll
    for (int a = 0; a < 15; ++a) v2[a] = sm[rl][16*a + b];   // own row
    float2 ZZ[16];
    fft240_core<+1>(sm, v2, ZZ, rl, b);     // ZZ[m] = 240*z[h=15m+b], col rl
    const float inv240 = 1.0f / 240.0f;
    if (b < 15){                            // own-row scatter (wave-local)
        #pragma unroll
        for (int m = 0; m < 16; ++m)
            sm[rl][15*m + b] = make_float2(ZZ[m].x*inv240, ZZ[m].y*inv240);
    }
    lds_barrier();                          // B4: tile complete + in-place WAR
    if (tid < 240){                         // staged float4 store, [h][c] order
        #pragma unroll
        for (int jj = 0; jj < 4; ++jj){
            int k = jj*240 + tid;
            int col = k >> 2;
            int r0 = (4*k) & 15;
            float4 outv;
            __half2* op = (__half2*)&outv;
            #pragma unroll
            for (int i = 0; i < 4; ++i) op[i] = f2h(sm[r0 + i][col]);
            *(float4*)(chunk + 4*k) = outv;  // 16 B/lane contiguous
        }
    }
}

// Pass C (PIPELINED, ZERO BARRIERS, unchanged): direct coalesced global->reg
// gather across the 15 [h][c] chunks, inverse row FFT, abs*1/240, store.
__global__ __launch_bounds__(256) void passC_irow_abs(const __half2* __restrict__ in,
                                                      float* __restrict__ outp){
    __shared__ __align__(16) float2 sm[16][PITCH];
    int g = blockIdx.x;
    int tid = threadIdx.x, rl = tid >> 4, b = tid & 15;
    float2 v[15];
    {
        int c = g*CHC; int img = c / NB, h0 = (c % NB) * 16;
        #pragma unroll
        for (int a = 0; a < 15; ++a)
            v[a] = h2f(in[((size_t)(img*NB + a)*HW + h0 + rl)*16 + b]);
    }
    const float inv240 = 1.0f / 240.0f;
    for (int t = 0; t < CHC; ++t){
        int c = g*CHC + t; int img = c / NB, h0 = (c % NB) * 16;
        float2 nv[15];
        if (t+1 < CHC){                     // prefetch next tile early
            int c2 = c + 1; int img2 = c2 / NB, h02 = (c2 % NB) * 16;
            #pragma unroll
            for (int a = 0; a < 15; ++a)
                nv[a] = h2f(in[((size_t)(img2*NB + a)*HW + h02 + rl)*16 + b]);
        }
        asm volatile("" ::: "memory");      // pin prefetch issue point
        float2 XX[16];
        fft240_core<+1>(sm, v, XX, rl, b);  // XX[m] = 240*z[w=15m+b], row h0+rl
        float* dst = outp + (size_t)img * IMG_PIX + (size_t)(h0 + rl) * HW;
        if (b < 15){
            #pragma unroll
            for (int m = 0; m < 16; ++m){
                float2 X = XX[m];
                dst[15*m + b] = sqrtf(X.x*X.x + X.y*X.y) * inv240;
            }
        }
        if (t+1 < CHC){
            #pragma unroll
            for (int a = 0; a < 15; ++a) v[a] = nv[a];
        }
    }
}

extern "C" void kernel_launch(void* const* d_in, const int* in_sizes, int n_in,
                              void* d_out, int out_size, void* d_ws, size_t ws_size,
                              hipStream_t stream){
    const float* T2   = (const float*)d_in[0];   // [256,1,240,240] f32
    const float* U    = (const float*)d_in[1];   // [256,2,240,240] f32
    const float* Am   = (const float*)d_in[2];   // [240,240] f32
    float* out        = (float*)d_out;           // [256,1,240,240] f32

    const int B = 256;
    __half2* i1 = (__half2*)d_ws;                // single 59 MB fp16 intermediate

    passA_rowfft     <<<dim3(B * NB),       dim3(128), 0, stream>>>(T2, i1);
    passB_col_dc_icol<<<dim3(B * NB),       dim3(256), 0, stream>>>(i1, U, Am);
    passC_irow_abs   <<<dim3(B * NB / CHC), dim3(256), 0, stream>>>(i1, out);
}